// Round 6
// baseline (57.578 us; speedup 1.0000x reference)
//
#include <hip/hip_runtime.h>

#define NN 160      // nodes
#define BB 128      // batch
#define HH 256      // hidden
#define EE 5120     // edges
#define ST 128      // state dim
#define AC 32       // action dim
#define HQ 64       // hidden quarter

typedef __attribute__((ext_vector_type(8))) short short8;
typedef __attribute__((ext_vector_type(4))) float f32x4;
typedef unsigned short us;

__device__ inline us f2b(float f) {
    unsigned u = __builtin_bit_cast(unsigned, f);
    unsigned r = (u + 0x7FFFu + ((u >> 16) & 1u)) >> 16;
    return (us)r;
}

// ---------- K1: graph rows + P row (int-exact) + weight transposes ----------
__global__ __launch_bounds__(256)
void k_pre(const int* __restrict__ ei, const float* __restrict__ W1,
           const float* __restrict__ W2, float* __restrict__ P,
           us* __restrict__ Mb, us* __restrict__ W1t, us* __restrict__ W2t)
{
    const int bx = blockIdx.x, tid = threadIdx.x;
    if (bx < NN) {
        __shared__ int crow[NN];
        __shared__ unsigned abit[NN * NN / 32];   // 3.2 KB
        __shared__ float invdeg;
        if (tid < NN) crow[tid] = 0;
        for (int i = tid; i < NN * NN / 32; i += 256) abit[i] = 0;
        __syncthreads();
        for (int e = tid; e < EE; e += 256) {
            int s = ei[e], d = ei[EE + e];
            int p = d * NN + s;
            atomicOr(&abit[p >> 5], 1u << (p & 31));
            if (d == bx) atomicAdd(&crow[s], 1);
        }
        if (tid < NN) {
            int p = tid * NN + tid;
            atomicOr(&abit[p >> 5], 1u << (p & 31));
        }
        __syncthreads();
        if (tid == 0) {
            int dg = 0;
            for (int j = 0; j < NN; j++) dg += crow[j];
            invdeg = 1.0f / (float)(dg < 1 ? 1 : dg);
        }
        __syncthreads();
        if (tid < NN) {
            int s = 0;
            for (int k = 0; k < NN; k++) {
                int p = k * NN + tid;
                if (abit[p >> 5] & (1u << (p & 31))) s += crow[k];
            }
            P[bx * NN + tid]  = (float)s * invdeg;
            Mb[bx * NN + tid] = f2b((float)crow[tid] * invdeg);
        }
    } else if (bx < NN + 160) {                   // W1t: 256x160
        int idx = (bx - NN) * 256 + tid;
        int n = idx / NN, k = idx - n * NN;
        W1t[idx] = f2b(W1[k * HH + n]);
    } else {                                      // W2t: 256x256
        int idx = (bx - NN - 160) * 256 + tid;
        int n = idx >> 8, k = idx & 255;
        W2t[idx] = f2b(W2[k * HH + n]);
    }
}

// ---------- K2: layer1 + agg2 per (h-quarter, batch). 512 blocks ----------
// GEMM1: h1[hh][i] = relu(sum_j W1t[ho+hh][j]*(P[i][j]*x[b][j]) + b1[ho+hh])
// GEMM2: t[b][i][ho+hh] = sum_k Mb[i][k]*h1[hh][k]
__global__ __launch_bounds__(256)
void k_l1agg(const float* __restrict__ P, const float* __restrict__ state,
             const float* __restrict__ action, const us* __restrict__ W1t,
             const float* __restrict__ b1, const us* __restrict__ Mb,
             const float* __restrict__ bo, us* __restrict__ t_out,
             float* __restrict__ out)
{
    constexpr int KS = 40;    // staging K-stride (shorts)
    constexpr int H1S = 168;  // h1 row stride
    __shared__ float xb[NN];
    __shared__ __align__(16) us h1[HQ][H1S];       // 21.5 KB
    __shared__ __align__(16) us stg[(NN + HQ) * KS]; // 17.9 KB
    us* sW = stg;             // [HQ][KS]  GEMM1 A
    us* sY = stg + HQ * KS;   // [NN][KS]  GEMM1 Bt
    us* sM = stg;             // [NN][KS]  GEMM2 A

    const int hq = blockIdx.x, b = blockIdx.y, ho = hq * HQ;
    const int tid = threadIdx.x, lane = tid & 63, w = tid >> 6;  // 4 waves
    const int wr = w >> 1, wc = w & 1;
    const int rl = lane & 15, kq = lane >> 4;

    if (tid < NN) xb[tid] = (tid < ST) ? state[b * ST + tid]
                                       : action[b * AC + (tid - ST)];
    if (hq == 0 && tid >= 128 && tid < 128 + ST)   // init out for K3's atomics
        out[b * ST + tid - 128] = state[b * ST + tid - 128] + bo[tid - 128];
    __syncthreads();

    // ---- GEMM1: M=64(h), N=160(i), K=160. waves 2x2: WM=32, WN=80
    {
        f32x4 acc[2][5];
#pragma unroll
        for (int f = 0; f < 2; f++)
#pragma unroll
            for (int j = 0; j < 5; j++) acc[f][j] = f32x4{0.f, 0.f, 0.f, 0.f};

        for (int k0 = 0; k0 < NN; k0 += 32) {
            for (int idx = tid; idx < 256 + 640; idx += 256) {
                if (idx < 256) {              // A: W1t quarter rows
                    int r = idx >> 2, c = (idx & 3) * 8;
                    *(short8*)&sW[r * KS + c] =
                        *(const short8*)&W1t[(size_t)(ho + r) * NN + k0 + c];
                } else {                      // Bt: Y = bf16(P*x) on the fly
                    int q = idx - 256;
                    int r = q >> 2, c = (q & 3) * 8;
                    const f32x4* p4 = (const f32x4*)&P[r * NN + k0 + c];
                    f32x4 p0 = p4[0], p1 = p4[1];
                    short8 y;
#pragma unroll
                    for (int u = 0; u < 4; u++) {
                        y[u]     = (short)f2b(p0[u] * xb[k0 + c + u]);
                        y[u + 4] = (short)f2b(p1[u] * xb[k0 + c + 4 + u]);
                    }
                    *(short8*)&sY[r * KS + c] = y;
                }
            }
            __syncthreads();
            short8 af[2], bf[5];
#pragma unroll
            for (int f = 0; f < 2; f++)
                af[f] = *(const short8*)&sW[(wr * 32 + f * 16 + rl) * KS + kq * 8];
#pragma unroll
            for (int j = 0; j < 5; j++)
                bf[j] = *(const short8*)&sY[(wc * 80 + j * 16 + rl) * KS + kq * 8];
#pragma unroll
            for (int f = 0; f < 2; f++)
#pragma unroll
                for (int j = 0; j < 5; j++)
                    acc[f][j] = __builtin_amdgcn_mfma_f32_16x16x32_bf16(
                        af[f], bf[j], acc[f][j], 0, 0, 0);
            __syncthreads();
        }
        // epilogue -> h1 (bias+relu). row(h)=wr*32+f*16+kq*4+r, col(i)=wc*80+j*16+rl
#pragma unroll
        for (int f = 0; f < 2; f++) {
            int rowb = wr * 32 + f * 16 + kq * 4;
#pragma unroll
            for (int j = 0; j < 5; j++) {
                int col = wc * 80 + j * 16 + rl;
#pragma unroll
                for (int r = 0; r < 4; r++) {
                    int row = rowb + r;
                    float v = acc[f][j][r] + b1[ho + row];
                    h1[row][col] = f2b(v > 0.f ? v : 0.f);
                }
            }
        }
    }
    __syncthreads();

    // ---- GEMM2: M=160(i), N=64(h), K=160. waves 2x2: WM=80, WN=32
    {
        f32x4 acc[5][2];
#pragma unroll
        for (int f = 0; f < 5; f++)
#pragma unroll
            for (int j = 0; j < 2; j++) acc[f][j] = f32x4{0.f, 0.f, 0.f, 0.f};

        for (int k0 = 0; k0 < NN; k0 += 32) {
            for (int idx = tid; idx < 640; idx += 256) {
                int r = idx >> 2, c = (idx & 3) * 8;
                *(short8*)&sM[r * KS + c] =
                    *(const short8*)&Mb[(size_t)r * NN + k0 + c];
            }
            __syncthreads();
            short8 af[5], bf[2];
#pragma unroll
            for (int f = 0; f < 5; f++)
                af[f] = *(const short8*)&sM[(wr * 80 + f * 16 + rl) * KS + kq * 8];
#pragma unroll
            for (int j = 0; j < 2; j++)
                bf[j] = *(const short8*)&h1[wc * 32 + j * 16 + rl][k0 + kq * 8];
#pragma unroll
            for (int f = 0; f < 5; f++)
#pragma unroll
                for (int j = 0; j < 2; j++)
                    acc[f][j] = __builtin_amdgcn_mfma_f32_16x16x32_bf16(
                        af[f], bf[j], acc[f][j], 0, 0, 0);
            __syncthreads();
        }
        // epilogue -> global t quarter
#pragma unroll
        for (int f = 0; f < 5; f++) {
            int rowb = wr * 80 + f * 16 + kq * 4;
#pragma unroll
            for (int j = 0; j < 2; j++) {
                int col = ho + wc * 32 + j * 16 + rl;
#pragma unroll
                for (int r = 0; r < 4; r++)
                    t_out[((size_t)b * NN + rowb + r) * HH + col] = f2b(acc[f][j][r]);
            }
        }
    }
}

// ---------- K3: mm2 + pool + head partial per (h-quarter, batch) ----------
// h2[i][h] = relu(sum_k t[b][i][k]*W2t[h][k] + b2[h]), h in quarter
// pp[h] = sum_i h2[i][h]; out[b][s] += (sum_h pp[h]*Wo[h][s])/NN  (atomic)
__global__ __launch_bounds__(256)
void k_mm2head(const us* __restrict__ t_in, const us* __restrict__ W2t,
               const float* __restrict__ b2, const float* __restrict__ Wo,
               float* __restrict__ out)
{
    constexpr int KS = 40;
    __shared__ __align__(16) us stg[(NN + HQ) * KS];  // 17.9 KB
    __shared__ float pp2[8][HQ];                       // 2 KB
    __shared__ float partials[2][ST];                  // 1 KB
    us* sT  = stg;             // [NN][KS]
    us* sW2 = stg + NN * KS;   // [HQ][KS]

    const int hq = blockIdx.x, b = blockIdx.y, ho = hq * HQ;
    const int tid = threadIdx.x, lane = tid & 63, w = tid >> 6;  // 4 waves
    const int wr = w >> 1, wc = w & 1;          // WM=80, WN=32
    const int rl = lane & 15, kq = lane >> 4;

    f32x4 acc[5][2];
#pragma unroll
    for (int f = 0; f < 5; f++)
#pragma unroll
        for (int j = 0; j < 2; j++) acc[f][j] = f32x4{0.f, 0.f, 0.f, 0.f};

    for (int k0 = 0; k0 < HH; k0 += 32) {
        for (int idx = tid; idx < 640 + 256; idx += 256) {
            if (idx < 640) {                  // A: t rows
                int r = idx >> 2, c = (idx & 3) * 8;
                *(short8*)&sT[r * KS + c] =
                    *(const short8*)&t_in[((size_t)b * NN + r) * HH + k0 + c];
            } else {                          // Bt: W2t quarter rows
                int q = idx - 640;
                int r = q >> 2, c = (q & 3) * 8;
                *(short8*)&sW2[r * KS + c] =
                    *(const short8*)&W2t[(size_t)(ho + r) * HH + k0 + c];
            }
        }
        __syncthreads();
        short8 af[5], bf[2];
#pragma unroll
        for (int f = 0; f < 5; f++)
            af[f] = *(const short8*)&sT[(wr * 80 + f * 16 + rl) * KS + kq * 8];
#pragma unroll
        for (int j = 0; j < 2; j++)
            bf[j] = *(const short8*)&sW2[(wc * 32 + j * 16 + rl) * KS + kq * 8];
#pragma unroll
        for (int f = 0; f < 5; f++)
#pragma unroll
            for (int j = 0; j < 2; j++)
                acc[f][j] = __builtin_amdgcn_mfma_f32_16x16x32_bf16(
                    af[f], bf[j], acc[f][j], 0, 0, 0);
        __syncthreads();
    }
    // epilogue: bias+relu, in-lane sum over rows, slotted store (deterministic)
    const int slot = wr * 4 + kq;
#pragma unroll
    for (int j = 0; j < 2; j++) {
        int lc = wc * 32 + j * 16 + rl;
        float bias = b2[ho + lc];
        float s = 0.f;
#pragma unroll
        for (int f = 0; f < 5; f++)
#pragma unroll
            for (int r = 0; r < 4; r++) {
                float v = acc[f][j][r] + bias;
                s += v > 0.f ? v : 0.f;
            }
        pp2[slot][lc] = s;
    }
    __syncthreads();
    // head partial over this quarter's 64 h values
    {
        const int q = tid >> 7, s = tid & 127;
        float part = 0.f;
        for (int lc = q * 32; lc < q * 32 + 32; lc++) {
            float pk = pp2[0][lc] + pp2[1][lc] + pp2[2][lc] + pp2[3][lc]
                     + pp2[4][lc] + pp2[5][lc] + pp2[6][lc] + pp2[7][lc];
            part += pk * Wo[(ho + lc) * ST + s];
        }
        partials[q][s] = part;
        __syncthreads();
        if (tid < ST)
            atomicAdd(&out[b * ST + tid],
                      (partials[0][tid] + partials[1][tid]) * (1.0f / NN));
    }
}

extern "C" void kernel_launch(void* const* d_in, const int* in_sizes, int n_in,
                              void* d_out, int out_size, void* d_ws, size_t ws_size,
                              hipStream_t stream) {
    const float* state  = (const float*)d_in[0];
    const float* action = (const float*)d_in[1];
    const int*   ei     = (const int*)d_in[2];
    const float* W1     = (const float*)d_in[3];
    const float* b1     = (const float*)d_in[4];
    const float* W2     = (const float*)d_in[5];
    const float* b2     = (const float*)d_in[6];
    const float* Wo     = (const float*)d_in[7];
    const float* bo     = (const float*)d_in[8];
    float* out = (float*)d_out;

    char* ws = (char*)d_ws;
    size_t off = 0;
    auto alloc = [&](size_t bytes) {
        void* p = ws + off;
        off += (bytes + 255) & ~(size_t)255;
        return p;
    };
    float* P   = (float*)alloc(NN * NN * 4);
    us* Mb  = (us*)alloc(NN * NN * 2);
    us* W1t = (us*)alloc((size_t)HH * NN * 2);
    us* W2t = (us*)alloc((size_t)HH * HH * 2);
    us* t   = (us*)alloc((size_t)BB * NN * HH * 2);

    k_pre<<<NN + 160 + 256, 256, 0, stream>>>(ei, W1, W2, P, Mb, W1t, W2t);
    {
        dim3 g(4, BB);   // 512 blocks
        k_l1agg<<<g, 256, 0, stream>>>(P, state, action, W1t, b1, Mb, bo, t, out);
    }
    {
        dim3 g(4, BB);   // 512 blocks
        k_mm2head<<<g, 256, 0, stream>>>(t, W2t, b2, Wo, out);
    }
}